// Round 7
// baseline (307.728 us; speedup 1.0000x reference)
//
#include <hip/hip_runtime.h>
#include <hip/hip_bf16.h>

typedef __bf16 bf16x8 __attribute__((ext_vector_type(8)));
typedef float f32x4 __attribute__((ext_vector_type(4)));
typedef unsigned short ushort_t;
typedef unsigned int uint_t;

#define HN 16
#define LSEQ 256
#define DD 1024
#define BB 4
#define SS 4096
#define MROWS (BB * SS) /* 16384 */
#define BHN (BB * HN)   /* 64 */

__device__ __forceinline__ ushort_t f2bf(float f) {
  uint_t u = __builtin_bit_cast(uint_t, f);
  u += 0x7fffu + ((u >> 16) & 1u); // RNE
  return (ushort_t)(u >> 16);
}
__device__ __forceinline__ uint_t cvtpk(float lo, float hi) {
  uint_t r;
  asm("v_cvt_pk_bf16_f32 %0, %1, %2" : "=v"(r) : "v"(lo), "v"(hi));
  return r;
}

// ---------- weight transpose x4: W fp32 [K][N] -> WT bf16 [N][K], packed ----------
__global__ __launch_bounds__(256) void transpose_w4(const float* __restrict__ W0,
                                                    const float* __restrict__ W1,
                                                    const float* __restrict__ W2,
                                                    const float* __restrict__ W3,
                                                    ushort_t* __restrict__ WT) {
  __shared__ float tile[32][33];
  const int z = blockIdx.z;
  const float* W = (z == 0) ? W0 : (z == 1) ? W1 : (z == 2) ? W2 : W3;
  ushort_t* dst = WT + (long)z * 1048576;
  const int tx = threadIdx.x, ty = threadIdx.y;
  const int bn = blockIdx.x * 32, bk = blockIdx.y * 32;
#pragma unroll
  for (int j = 0; j < 32; j += 8)
    tile[ty + j][tx] = W[(long)(bk + ty + j) * DD + bn + tx];
  __syncthreads();
#pragma unroll
  for (int j = 0; j < 32; j += 8)
    dst[(long)(bn + ty + j) * DD + bk + tx] = f2bf(tile[tx][ty + j]);
}

// ---------- vh transpose per (b,h): [256][1024] -> [1024][256] bf16 ----------
__global__ __launch_bounds__(256) void transpose_v(const ushort_t* __restrict__ vh,
                                                   ushort_t* __restrict__ vhT) {
  __shared__ ushort_t tile[32][33];
  const int tx = threadIdx.x, ty = threadIdx.y;
  const long zo = (long)blockIdx.z * (LSEQ * DD);
  const ushort_t* src = vh + zo;
  ushort_t* dst = vhT + zo;
  const int bd = blockIdx.x * 32; // d
  const int bl = blockIdx.y * 32; // l
#pragma unroll
  for (int j = 0; j < 32; j += 8)
    tile[ty + j][tx] = src[(long)(bl + ty + j) * DD + bd + tx];
  __syncthreads();
#pragma unroll
  for (int j = 0; j < 32; j += 8)
    dst[(long)(bd + ty + j) * LSEQ + bl + tx] = tile[tx][ty + j];
}

// ---------- fused scores + mask + softmax ----------
__global__ __launch_bounds__(256, 2) void score_sm(const ushort_t* __restrict__ qh,
                                                   const ushort_t* __restrict__ kh,
                                                   const int* __restrict__ mask,
                                                   ushort_t* __restrict__ att) {
  __shared__ char smemraw[81920];
  ushort_t* sA = (ushort_t*)smemraw;
  ushort_t* sB = (ushort_t*)(smemraw + 16384);
  float* Sf = (float*)smemraw;

  const int orig = blockIdx.x;
  const int wgid = (orig & 7) * 32 + (orig >> 3);
  const int bh = wgid >> 2, rb = wgid & 3;
  const int b = bh >> 4;
  const ushort_t* A = qh + ((long)bh * 256 + rb * 64) * 1024;
  const ushort_t* Bk = kh + (long)bh * 256 * 1024;

  const int t = threadIdx.x, lane = t & 63, wid = t >> 6;
  const int fr = lane & 15, q = lane >> 4;
  const int wc = wid * 64;
  const int sw0 = (q ^ (fr & 7)) * 8;
  const int sw1 = ((4 + q) ^ (fr & 7)) * 8;

  int srcAo[2], dstA[2], srcBo[8], dstB[8];
#pragma unroll
  for (int i = 0; i < 2; ++i) {
    const int c = i * 256 + t, row = c >> 3, gc = (c & 7) ^ (row & 7);
    srcAo[i] = row * 1024 + gc * 8;
    dstA[i] = (i * 256 + (t & 192)) * 8;
  }
#pragma unroll
  for (int i = 0; i < 8; ++i) {
    const int c = i * 256 + t, row = c >> 3, gc = (c & 7) ^ (row & 7);
    srcBo[i] = row * 1024 + gc * 8;
    dstB[i] = (i * 256 + (t & 192)) * 8;
  }

  auto stage = [&](int buf, int kt) {
    const int ko = kt * 64;
#pragma unroll
    for (int i = 0; i < 2; ++i)
      __builtin_amdgcn_global_load_lds(
          (const __attribute__((address_space(1))) void*)(A + srcAo[i] + ko),
          (__attribute__((address_space(3))) void*)(sA + buf * 4096 + dstA[i]), 16, 0, 0);
#pragma unroll
    for (int i = 0; i < 8; ++i)
      __builtin_amdgcn_global_load_lds(
          (const __attribute__((address_space(1))) void*)(Bk + srcBo[i] + ko),
          (__attribute__((address_space(3))) void*)(sB + buf * 16384 + dstB[i]), 16, 0, 0);
  };

  f32x4 acc[4][4];
#pragma unroll
  for (int m = 0; m < 4; ++m)
#pragma unroll
    for (int n = 0; n < 4; ++n) acc[m][n] = (f32x4){0.f, 0.f, 0.f, 0.f};

  stage(0, 0);
  __syncthreads();
  int cur = 0;
  for (int kt = 0; kt < 16; ++kt) {
    if (kt < 15) stage(cur ^ 1, kt + 1);
    bf16x8 af[4][2], bfv[4][2];
    const ushort_t* bA = sA + cur * 4096;
    const ushort_t* bB = sB + cur * 16384;
#pragma unroll
    for (int m = 0; m < 4; ++m) {
      af[m][0] = *(const bf16x8*)(bA + (m * 16 + fr) * 64 + sw0);
      af[m][1] = *(const bf16x8*)(bA + (m * 16 + fr) * 64 + sw1);
    }
#pragma unroll
    for (int n = 0; n < 4; ++n) {
      bfv[n][0] = *(const bf16x8*)(bB + (wc + n * 16 + fr) * 64 + sw0);
      bfv[n][1] = *(const bf16x8*)(bB + (wc + n * 16 + fr) * 64 + sw1);
    }
#pragma unroll
    for (int m = 0; m < 4; ++m)
#pragma unroll
      for (int n = 0; n < 4; ++n) {
        acc[m][n] = __builtin_amdgcn_mfma_f32_16x16x32_bf16(af[m][0], bfv[n][0], acc[m][n], 0, 0, 0);
        acc[m][n] = __builtin_amdgcn_mfma_f32_16x16x32_bf16(af[m][1], bfv[n][1], acc[m][n], 0, 0, 0);
      }
    __syncthreads();
    cur ^= 1;
  }

#pragma unroll
  for (int m = 0; m < 4; ++m)
#pragma unroll
    for (int n = 0; n < 4; ++n)
#pragma unroll
      for (int r = 0; r < 4; ++r)
        Sf[(m * 16 + q * 4 + r) * 256 + wc + n * 16 + fr] = acc[m][n][r];
  __syncthreads();

#pragma unroll 2
  for (int i = 0; i < 16; ++i) {
    const int row = wid * 16 + i;
    const int gl = rb * 64 + row;
    const f32x4 sv = *(const f32x4*)&Sf[row * 256 + lane * 4];
    const int4 mv = *(const int4*)&mask[((long)b * 256 + gl) * 256 + lane * 4];
    float s[4];
    s[0] = (mv.x == 0) ? 1e-9f : sv[0] * 0.03125f;
    s[1] = (mv.y == 0) ? 1e-9f : sv[1] * 0.03125f;
    s[2] = (mv.z == 0) ? 1e-9f : sv[2] * 0.03125f;
    s[3] = (mv.w == 0) ? 1e-9f : sv[3] * 0.03125f;
    float mx = fmaxf(fmaxf(s[0], s[1]), fmaxf(s[2], s[3]));
#pragma unroll
    for (int off = 32; off; off >>= 1) mx = fmaxf(mx, __shfl_xor(mx, off));
    float e[4], sum = 0.f;
#pragma unroll
    for (int j = 0; j < 4; ++j) {
      e[j] = __expf(s[j] - mx);
      sum += e[j];
    }
#pragma unroll
    for (int off = 32; off; off >>= 1) sum += __shfl_xor(sum, off);
    const float inv = 1.0f / sum;
    ushort4 o;
    o.x = f2bf(e[0] * inv);
    o.y = f2bf(e[1] * inv);
    o.z = f2bf(e[2] * inv);
    o.w = f2bf(e[3] * inv);
    *(ushort4*)&att[((long)bh * 256 + gl) * 256 + lane * 4] = o;
  }
}

// ---------- 128^2 TN GEMM (batched PV), bf16 pv-permute store ----------
template <int SMODE>
__global__ __launch_bounds__(256, 2) void gemm_tn(const ushort_t* __restrict__ Ab,
                                                  const ushort_t* __restrict__ Btp,
                                                  void* __restrict__ Cp, int K, int ldA,
                                                  int ldB, int ldC, long batchA,
                                                  long batchB, long batchC) {
  __shared__ ushort_t smem[16384];
  ushort_t* sA = smem;
  ushort_t* sB = smem + 8192;

  const int bx = blockIdx.x, by = blockIdx.y, z = blockIdx.z;
  const int rowBase = by * 128;
  const int colBase = bx * 128;

  const int t = threadIdx.x;
  const int lane = t & 63;
  const int wid = t >> 6;
  const int wr = (wid >> 1) * 64;
  const int wc = (wid & 1) * 64;
  const int fr = lane & 15;
  const int fk = (lane >> 4) * 8;

  const ushort_t* Atile = Ab + batchA * z + (long)rowBase * ldA;
  const ushort_t* Btile = Btp + batchB * z + (long)colBase * ldB;

  f32x4 acc[4][4];
#pragma unroll
  for (int m = 0; m < 4; ++m)
#pragma unroll
    for (int n = 0; n < 4; ++n) acc[m][n] = (f32x4){0.f, 0.f, 0.f, 0.f};

  const int NT = K >> 5;

  auto stageAB = [&](int buf, int kt) {
    const long ko = (long)kt * 32;
#pragma unroll
    for (int i = 0; i < 2; ++i) {
      const int c = i * 256 + t;
      const int cw = i * 256 + (t & 192);
      __builtin_amdgcn_global_load_lds(
          (const __attribute__((address_space(1))) void*)(Atile + (long)(c >> 2) * ldA + ko +
                                                          (c & 3) * 8),
          (__attribute__((address_space(3))) void*)(sA + buf * 4096 + cw * 8), 16, 0, 0);
      __builtin_amdgcn_global_load_lds(
          (const __attribute__((address_space(1))) void*)(Btile + (long)(c >> 2) * ldB + ko +
                                                          (c & 3) * 8),
          (__attribute__((address_space(3))) void*)(sB + buf * 4096 + cw * 8), 16, 0, 0);
    }
  };

  stageAB(0, 0);
  __syncthreads();

  int cur = 0;
  for (int kt = 0; kt < NT; ++kt) {
    if (kt + 1 < NT) stageAB(cur ^ 1, kt + 1);

    bf16x8 af[4], bfv[4];
    const ushort_t* baseA = sA + cur * 4096 + fk;
    const ushort_t* baseB = sB + cur * 4096 + fk;
#pragma unroll
    for (int m = 0; m < 4; ++m) af[m] = *(const bf16x8*)(baseA + (wr + m * 16 + fr) * 32);
#pragma unroll
    for (int n = 0; n < 4; ++n) bfv[n] = *(const bf16x8*)(baseB + (wc + n * 16 + fr) * 32);

#pragma unroll
    for (int m = 0; m < 4; ++m)
#pragma unroll
      for (int n = 0; n < 4; ++n)
        acc[m][n] = __builtin_amdgcn_mfma_f32_16x16x32_bf16(af[m], bfv[n], acc[m][n], 0, 0, 0);

    __syncthreads();
    cur ^= 1;
  }

  const int rq = (lane >> 4) * 4;
  {
#pragma unroll
    for (int m = 0; m < 4; ++m)
#pragma unroll
      for (int n = 0; n < 4; ++n)
#pragma unroll
        for (int r = 0; r < 4; ++r)
          smem[(wr + m * 16 + rq + r) * 128 + wc + n * 16 + fr] = f2bf(acc[m][n][r]);
    __syncthreads();
    ushort_t* Cb = (ushort_t*)Cp;
    const int c8 = (lane & 15) * 8;
#pragma unroll
    for (int i = 0; i < 8; ++i) {
      const int row = i * 16 + wid * 4 + (lane >> 4);
      const uint4 val = *(const uint4*)(smem + row * 128 + c8);
      const int l = rowBase + row;
      const int orow = ((z >> 4) << 12) + l * 16 + (z & 15); // b*4096 + l*16 + h
      *(uint4*)(Cb + (long)orow * 1024 + colBase + c8) = val;
    }
  }
}

#define SBAR() asm volatile("s_barrier" ::: "memory")
#define LGKM0() asm volatile("s_waitcnt lgkmcnt(0)" ::: "memory")
#define VM(N) asm volatile("s_waitcnt vmcnt(" #N ")" ::: "memory")

// ---------- 256^2 8-phase TN GEMM, bf16 A (for final x@Wo) ----------
template <int SMODE>
__global__ __launch_bounds__(512, 1) void gemm256(const ushort_t* __restrict__ A0,
                                                  const ushort_t* __restrict__ Btp,
                                                  void* __restrict__ Cp) {
  __shared__ ushort_t sm[65536];

  const int orig = blockIdx.x;
  const int cpx = (int)gridDim.x >> 3;
  const int wgid = (orig & 7) * cpx + (orig >> 3);
  const int by = wgid >> 2, bx = wgid & 3;
  const int rowBase = by * 256, colBase = bx * 256;

  const ushort_t* Ab = A0;
  const ushort_t* Bt = Btp;

  const int t = threadIdx.x;
  const int lane = t & 63;
  const int wid = t >> 6;
  const int wm = wid >> 2;
  const int wn = wid & 3;
  const int fr = lane & 15;
  const int q = lane >> 4;

  const int sw0 = ((q ^ (fr & 7)) * 8);
  const int sw1 = (((4 + q) ^ (fr & 7)) * 8);
  const int aoff0 = fr * 64 + sw0;
  const int aoff1 = fr * 64 + sw1;
  const int bbase = ((wn & 1) * 64 + fr) * 64;
  const int boff0 = bbase + sw0;
  const int boff1 = bbase + sw1;

  const ushort_t* srcA[2][2];
  const ushort_t* srcB[2][2];
  int ldsoff[2];
#pragma unroll
  for (int i = 0; i < 2; ++i) {
    const int c = i * 512 + t;
    const int rowc = c >> 3;
    const int gc = (c & 7) ^ (rowc & 7);
    srcA[0][i] = Ab + (long)(rowBase + rowc) * 1024 + gc * 8;
    srcA[1][i] = Ab + (long)(rowBase + 128 + rowc) * 1024 + gc * 8;
    srcB[0][i] = Bt + (long)(colBase + rowc) * 1024 + gc * 8;
    srcB[1][i] = Bt + (long)(colBase + 128 + rowc) * 1024 + gc * 8;
    ldsoff[i] = (c & ~63) * 8;
  }

#define STAGE(kind, h, T)                                                                   \
  do {                                                                                      \
    ushort_t* _d = sm + ((kind) ? 32768 : 0) + ((T) & 1) * 16384 + (h) * 8192;              \
    const ushort_t* _s0 = ((kind) ? srcB[h][0] : srcA[h][0]) + (long)(T) * 64;              \
    __builtin_amdgcn_global_load_lds((const __attribute__((address_space(1))) void*)_s0,    \
                                     (__attribute__((address_space(3))) void*)(_d + ldsoff[0]), \
                                     16, 0, 0);                                             \
    const ushort_t* _s1 = ((kind) ? srcB[h][1] : srcA[h][1]) + (long)(T) * 64;              \
    __builtin_amdgcn_global_load_lds((const __attribute__((address_space(1))) void*)_s1,    \
                                     (__attribute__((address_space(3))) void*)(_d + ldsoff[1]), \
                                     16, 0, 0);                                             \
  } while (0)

  f32x4 acc[8][4];
#pragma unroll
  for (int m = 0; m < 8; ++m)
#pragma unroll
    for (int n = 0; n < 4; ++n) acc[m][n] = (f32x4){0.f, 0.f, 0.f, 0.f};

  bf16x8 af[4][2], bf0[2][2], bf1[2][2];

#define LDA4(dbuf, msub)                                                         \
  do {                                                                           \
    const ushort_t* _b = sm + (dbuf)*16384 + wm * 8192 + (msub)*4096;            \
    _Pragma("unroll") for (int m2 = 0; m2 < 4; ++m2) {                           \
      af[m2][0] = *(const bf16x8*)(_b + m2 * 1024 + aoff0);                      \
      af[m2][1] = *(const bf16x8*)(_b + m2 * 1024 + aoff1);                      \
    }                                                                            \
  } while (0)

#define LDB2(dbuf, nsub, bfv)                                                    \
  do {                                                                           \
    const ushort_t* _b = sm + 32768 + (dbuf)*16384 + (wn >> 1) * 8192 + (nsub)*2048; \
    _Pragma("unroll") for (int n2 = 0; n2 < 2; ++n2) {                           \
      bfv[n2][0] = *(const bf16x8*)(_b + n2 * 1024 + boff0);                     \
      bfv[n2][1] = *(const bf16x8*)(_b + n2 * 1024 + boff1);                     \
    }                                                                            \
  } while (0)

#define MMQ(msub, nsub, bfv)                                                     \
  do {                                                                           \
    _Pragma("unroll") for (int m2 = 0; m2 < 4; ++m2)                             \
        _Pragma("unroll") for (int n2 = 0; n2 < 2; ++n2) {                       \
      acc[(msub)*4 + m2][(nsub)*2 + n2] = __builtin_amdgcn_mfma_f32_16x16x32_bf16( \
          af[m2][0], bfv[n2][0], acc[(msub)*4 + m2][(nsub)*2 + n2], 0, 0, 0);    \
      acc[(msub)*4 + m2][(nsub)*2 + n2] = __builtin_amdgcn_mfma_f32_16x16x32_bf16( \
          af[m2][1], bfv[n2][1], acc[(msub)*4 + m2][(nsub)*2 + n2], 0, 0, 0);    \
    }                                                                            \
  } while (0)

#define PH_OPEN() SBAR(); LGKM0(); __builtin_amdgcn_s_setprio(1)
#define PH_CLOSE() __builtin_amdgcn_s_setprio(0); SBAR()

  const int NT = 16;
  const int NI = 8;

  STAGE(0, 0, 0);
  STAGE(0, 1, 0);
  STAGE(1, 0, 0);
  STAGE(1, 1, 0);
  STAGE(0, 0, 1);
  VM(2);
  SBAR();

  for (int it = 0; it < NI - 1; ++it) {
    const int T0 = 2 * it;
    LDA4(0, 0);
    LDB2(0, 0, bf0);
    STAGE(0, 1, T0 + 1);
    PH_OPEN(); MMQ(0, 0, bf0); PH_CLOSE();
    LDB2(0, 1, bf1);
    STAGE(1, 0, T0 + 1);
    PH_OPEN(); MMQ(0, 1, bf1); PH_CLOSE();
    LDA4(0, 1);
    STAGE(1, 1, T0 + 1);
    PH_OPEN(); MMQ(1, 1, bf1); PH_CLOSE();
    STAGE(0, 0, T0 + 2);
    SBAR();
    __builtin_amdgcn_s_setprio(1);
    MMQ(1, 0, bf0);
    __builtin_amdgcn_s_setprio(0);
    VM(2);
    SBAR();
    LDA4(1, 0);
    LDB2(1, 0, bf0);
    STAGE(0, 1, T0 + 2);
    PH_OPEN(); MMQ(0, 0, bf0); PH_CLOSE();
    LDB2(1, 1, bf1);
    STAGE(1, 0, T0 + 2);
    PH_OPEN(); MMQ(0, 1, bf1); PH_CLOSE();
    LDA4(1, 1);
    STAGE(1, 1, T0 + 2);
    PH_OPEN(); MMQ(1, 1, bf1); PH_CLOSE();
    STAGE(0, 0, T0 + 3);
    SBAR();
    __builtin_amdgcn_s_setprio(1);
    MMQ(1, 0, bf0);
    __builtin_amdgcn_s_setprio(0);
    VM(2);
    SBAR();
  }

  {
    LDA4(0, 0);
    LDB2(0, 0, bf0);
    STAGE(0, 1, NT - 1);
    PH_OPEN(); MMQ(0, 0, bf0); PH_CLOSE();
    LDB2(0, 1, bf1);
    STAGE(1, 0, NT - 1);
    PH_OPEN(); MMQ(0, 1, bf1); PH_CLOSE();
    LDA4(0, 1);
    STAGE(1, 1, NT - 1);
    PH_OPEN(); MMQ(1, 1, bf1); PH_CLOSE();
    SBAR();
    __builtin_amdgcn_s_setprio(1);
    MMQ(1, 0, bf0);
    __builtin_amdgcn_s_setprio(0);
    VM(0);
    SBAR();
    LDA4(1, 0);
    LDB2(1, 0, bf0);
    PH_OPEN(); MMQ(0, 0, bf0); PH_CLOSE();
    LDB2(1, 1, bf1);
    PH_OPEN(); MMQ(0, 1, bf1); PH_CLOSE();
    LDA4(1, 1);
    PH_OPEN(); MMQ(1, 1, bf1); PH_CLOSE();
    SBAR();
    MMQ(1, 0, bf0);
    SBAR();
  }

  const int rq = q * 4;
  if constexpr (SMODE == 0) {
    float* Cf = (float*)Cp;
#pragma unroll
    for (int m = 0; m < 8; ++m)
#pragma unroll
      for (int n = 0; n < 4; ++n)
#pragma unroll
        for (int r = 0; r < 4; ++r) {
          const int row = rowBase + wm * 128 + m * 16 + rq + r;
          const int col = colBase + wn * 64 + n * 16 + fr;
          Cf[(long)row * 1024 + col] = acc[m][n][r];
        }
  }
#undef STAGE
}

// ---------- 256^2 8-phase TN GEMM, FP32 A reg-staged, counted-vmcnt ledger ----------
// z-batched: q,k,v fp32 [16384][1024] -> qh/kh/vh bf16 proj-permuted. grid 768x512.
// Steady-state queue (per half-iter U): PhA issues SB(U+1)x2 [4 ld], PhB IAh0(U+2) [4],
// PhC IAh1(U+2) [4]. Waits: VM(4)@PhA (IAh0(U+1) done, 3 phases old) -> WA h0;
// VM(4)@PhB (IAh1(U+1)) -> WA h1; VM(8)@PhD (SB(U+1) done, 3 phases old). Never 0.
__global__ __launch_bounds__(512, 1) void gemm256f(const float* __restrict__ A0,
                                                   const float* __restrict__ A1,
                                                   const float* __restrict__ A2,
                                                   const ushort_t* __restrict__ Btp,
                                                   ushort_t* __restrict__ Cp) {
  __shared__ ushort_t sm[65536]; // A dbuf 2x16K-elem, B dbuf 2x16K-elem (128KB)

  const int orig = blockIdx.x;
  const int cpx = (int)gridDim.x >> 3; // 96
  const int wgid = (orig & 7) * cpx + (orig >> 3);
  const int z = wgid >> 8;
  const int tile = wgid & 255;
  const int by = tile >> 2, bx = tile & 3;
  const int rowBase = by * 256, colBase = bx * 256;

  const float* Af = (z == 0) ? A0 : (z == 1) ? A1 : A2;
  const ushort_t* Bt = Btp + (long)z * 1048576;

  const int t = threadIdx.x;
  const int lane = t & 63;
  const int wid = t >> 6;
  const int wm = wid >> 2;
  const int wn = wid & 3;
  const int fr = lane & 15;
  const int q = lane >> 4;

  const int sw0 = ((q ^ (fr & 7)) * 8);
  const int sw1 = (((4 + q) ^ (fr & 7)) * 8);
  const int aoff0 = fr * 64 + sw0;
  const int aoff1 = fr * 64 + sw1;
  const int bbase = ((wn & 1) * 64 + fr) * 64;
  const int boff0 = bbase + sw0;
  const int boff1 = bbase + sw1;

  // B staging (global_load_lds, XOR-pre-swizzled source)
  const ushort_t* srcB[2][2];
  int ldsoff[2];
#pragma unroll
  for (int i = 0; i < 2; ++i) {
    const int c = i * 512 + t;
    const int rowc = c >> 3;
    const int gc = (c & 7) ^ (rowc & 7);
    srcB[0][i] = Bt + (long)(colBase + rowc) * 1024 + gc * 8;
    srcB[1][i] = Bt + (long)(colBase + 128 + rowc) * 1024 + gc * 8;
    ldsoff[i] = (c & ~63) * 8;
  }

  // A reg-staging: thread t owns row tr=t>>2 of a 128-row half, 16 contiguous cols
  const int tr = t >> 2;
  const int tc = (t & 3) * 16;
  const float* aSrc[2];
  aSrc[0] = Af + (long)(rowBase + tr) * 1024 + tc;
  aSrc[1] = Af + (long)(rowBase + 128 + tr) * 1024 + tc;
  const int j0 = (t & 3) * 2;
  const int wdst0 = tr * 64 + ((j0 ^ (tr & 7)) * 8);
  const int wdst1 = tr * 64 + (((j0 + 1) ^ (tr & 7)) * 8);

  float4 rsP[8], rsN[8]; // two A-tiles in flight (halves 0,1 = [0..3],[4..7])

#define SB(h, T)                                                                            \
  do {                                                                                      \
    ushort_t* _d = sm + 32768 + ((T) & 1) * 16384 + (h) * 8192;                             \
    __builtin_amdgcn_global_load_lds(                                                       \
        (const __attribute__((address_space(1))) void*)(srcB[h][0] + (long)(T) * 64),       \
        (__attribute__((address_space(3))) void*)(_d + ldsoff[0]), 16, 0, 0);               \
    __builtin_amdgcn_global_load_lds(                                                       \
        (const __attribute__((address_space(1))) void*)(srcB[h][1] + (long)(T) * 64),       \
        (__attribute__((address_space(3))) void*)(_d + ldsoff[1]), 16, 0, 0);               \
  } while (0)

#define IAh(rs, h, T)                                                                       \
  do {                                                                                      \
    const float* _p = aSrc[h] + (T) * 64;                                                   \
    rs[(h)*4 + 0] = *(const float4*)(_p);                                                   \
    rs[(h)*4 + 1] = *(const float4*)(_p + 4);                                               \
    rs[(h)*4 + 2] = *(const float4*)(_p + 8);                                               \
    rs[(h)*4 + 3] = *(const float4*)(_p + 12);                                              \
  } while (0)

#define WAh(rs, h, T)                                                                       \
  do {                                                                                      \
    ushort_t* _b = sm + ((T) & 1) * 16384 + (h) * 8192;                                     \
    uint4 _w0, _w1;                                                                         \
    _w0.x = cvtpk(rs[(h)*4 + 0].x, rs[(h)*4 + 0].y);                                        \
    _w0.y = cvtpk(rs[(h)*4 + 0].z, rs[(h)*4 + 0].w);                                        \
    _w0.z = cvtpk(rs[(h)*4 + 1].x, rs[(h)*4 + 1].y);                                        \
    _w0.w = cvtpk(rs[(h)*4 + 1].z, rs[(h)*4 + 1].w);                                        \
    _w1.x = cvtpk(rs[(h)*4 + 2].x, rs[(h)*4 + 2].y);                                        \
    _w1.y = cvtpk(rs[(h)*4 + 2].z, rs[(h)*4 + 2].w);                                        \
    _w1.z = cvtpk(rs[(h)*4 + 3].x, rs[(h)*4 + 3].y);                                        \
    _w1.w = cvtpk(rs[(h)*4 + 3].z, rs[(h)*4 + 3].w);                                        \
    *(uint4*)(_b + wdst0) = _w0;                                                            \
    *(uint4*)(_b + wdst1) = _w1;                                                            \
  } while (0)

  f32x4 acc[8][4];
#pragma unroll
  for (int m = 0; m < 8; ++m)
#pragma unroll
    for (int n = 0; n < 4; ++n) acc[m][n] = (f32x4){0.f, 0.f, 0.f, 0.f};

  bf16x8 af[4][2], bf0[2][2], bf1[2][2];

  const int NT = 16;

  // ---- prologue ----
  // issue IA(0) both halves [8], SB(0) [4]  -> 12 outstanding
  IAh(rsP, 0, 0);
  IAh(rsP, 1, 0);
  SB(0, 0);
  SB(1, 0);
  VM(4); // IA(0) done (8 oldest), SB(0) still in flight
  WAh(rsP, 0, 0);
  WAh(rsP, 1, 0);
  IAh(rsP, 0, 1);
  IAh(rsP, 1, 1); // tile1 A into rsP -> 12 outstanding
  VM(8);          // drain SB(0); leaves IA(1)[8] = steady invariant
  LGKM0();
  SBAR();

  // ---- steady half-iter macro: tile U from dbuf D; WA tile U+1 from RSW;
  //      IA tile U+2 into RSL; SB tile U+1. ----
#define ITER(U, RSW, RSL, D)                                                                \
  do {                                                                                      \
    /* PhA */                                                                               \
    VM(4); /* IAh0(U+1) landed */                                                           \
    WAh(RSW, 0, (U) + 1);                                                                   \
    SB(0, (U) + 1);                                                                         \
    SB(1, (U) + 1);                                                                         \
    LDA4(D, 0);                                                                             \
    LDB2(D, 0, bf0);                                                                        \
    PH_OPEN(); MMQ(0, 0, bf0); PH_CLOSE();                                                  \
    /* PhB */                                                                               \
    VM(4); /* IAh1(U+1) landed */                                                           \
    WAh(RSW, 1, (U) + 1);                                                                   \
    IAh(RSL, 0, (U) + 2);                                                                   \
    LDB2(D, 1, bf1);                                                                        \
    PH_OPEN(); MMQ(0, 1, bf1); PH_CLOSE();                                                  \
    /* PhC */                                                                               \
    LDA4(D, 1);                                                                             \
    IAh(RSL, 1, (U) + 2);                                                                   \
    PH_OPEN(); MMQ(1, 1, bf1); PH_CLOSE();                                                  \
    /* PhD */                                                                               \
    SBAR();                                                                                 \
    __builtin_amdgcn_s_setprio(1);                                                          \
    MMQ(1, 0, bf0);                                                                         \
    __builtin_amdgcn_s_setprio(0);                                                          \
    VM(8); /* SB(U+1) landed; IA(U+2)[8] remain */                                          \
    SBAR();                                                                                 \
  } while (0)

  // 14 steady half-iters, unrolled x2 for static reg-set alternation
#pragma unroll 1
  for (int u2 = 0; u2 < 7; ++u2) {
    const int U0 = 2 * u2;
    ITER(U0, rsP, rsN, 0);
    ITER(U0 + 1, rsN, rsP, 1);
  }

  // ---- peeled U = 14 (d=0): WA tile15 from rsP, SB tile15; no IA ----
  {
    VM(4);
    WAh(rsP, 0, 15);
    SB(0, 15);
    SB(1, 15);
    LDA4(0, 0);
    LDB2(0, 0, bf0);
    PH_OPEN(); MMQ(0, 0, bf0); PH_CLOSE();
    VM(4); // IAh1(15) landed (oldest 4; SB(15) in flight)
    WAh(rsP, 1, 15);
    LDB2(0, 1, bf1);
    PH_OPEN(); MMQ(0, 1, bf1); PH_CLOSE();
    LDA4(0, 1);
    PH_OPEN(); MMQ(1, 1, bf1); PH_CLOSE();
    SBAR();
    __builtin_amdgcn_s_setprio(1);
    MMQ(1, 0, bf0);
    __builtin_amdgcn_s_setprio(0);
    VM(0); // drain SB(15) — queue is only SB now, epilogue of pipe
    SBAR();
  }
  // ---- peeled U = 15 (d=1): pure compute ----
  {
    LDA4(1, 0);
    LDB2(1, 0, bf0);
    PH_OPEN(); MMQ(0, 0, bf0); PH_CLOSE();
    LDB2(1, 1, bf1);
    PH_OPEN(); MMQ(0, 1, bf1); PH_CLOSE();
    LDA4(1, 1);
    PH_OPEN(); MMQ(1, 1, bf1); PH_CLOSE();
    SBAR();
    MMQ(1, 0, bf0);
    SBAR();
  }

  // ---- epilogue: bf16 proj-permute via swizzled LDS C-tile ----
  const int rq = q * 4;
#pragma unroll
  for (int m = 0; m < 8; ++m)
#pragma unroll
    for (int n = 0; n < 4; ++n)
#pragma unroll
      for (int r = 0; r < 4; ++r) {
        const int row = wm * 128 + m * 16 + rq + r;
        const int col = wn * 64 + n * 16 + fr;
        sm[row * 256 + (((col >> 3) ^ (row & 7)) * 8) + (col & 7)] = f2bf(acc[m][n][r]);
      }
  __syncthreads();
  ushort_t* Cb = Cp + (long)z * 16777216;
  const int cc = t & 31;
  const int r0 = t >> 5;
#pragma unroll
  for (int i = 0; i < 16; ++i) {
    const int row = r0 + i * 16;
    const uint4 val = *(const uint4*)(sm + row * 256 + ((cc ^ (row & 7)) * 8));
    const int grow = rowBase + row; // = b*4096 + s, s = l*16+h
    const int b = grow >> 12;
    const int s = grow & 4095;
    const int orow = ((b << 4) + (s & 15)) * 256 + (s >> 4); // (b*16+h)*256 + l
    *(uint4*)(Cb + (long)orow * 1024 + colBase + cc * 8) = val;
  }
#undef SB
#undef IAh
#undef WAh
#undef ITER
#undef LDA4
#undef LDB2
#undef MMQ
#undef PH_OPEN
#undef PH_CLOSE
}

extern "C" void kernel_launch(void* const* d_in, const int* in_sizes, int n_in,
                              void* d_out, int out_size, void* d_ws, size_t ws_size,
                              hipStream_t stream) {
  const float* q = (const float*)d_in[0];
  const float* k = (const float*)d_in[1];
  const float* v = (const float*)d_in[2];
  const int* mask = (const int*)d_in[3];
  const float* Wq = (const float*)d_in[4];
  const float* Wk = (const float*)d_in[5];
  const float* Wv = (const float*)d_in[6];
  const float* Wo = (const float*)d_in[7];
  float* out = (float*)d_out;

  char* ws = (char*)d_ws;
  const size_t MB = 1024 * 1024;
  // layout (peak 176 MB): WT 0..8 | qh 8..40 | kh 40..72 | vh 72..104 | vhT 104..136
  //                       | att 136..144 | x 144..176
  ushort_t* WT = (ushort_t*)ws;
  ushort_t* qh = (ushort_t*)(ws + 8 * MB);
  ushort_t* kh = (ushort_t*)(ws + 40 * MB);
  ushort_t* vh = (ushort_t*)(ws + 72 * MB);
  ushort_t* vhT = (ushort_t*)(ws + 104 * MB);
  ushort_t* att = (ushort_t*)(ws + 136 * MB);
  ushort_t* x = (ushort_t*)(ws + 144 * MB);

  const dim3 tb(32, 8);
  transpose_w4<<<dim3(32, 32, 4), tb, 0, stream>>>(Wq, Wk, Wv, Wo, WT);

  // fused fp32->bf16 + projection: q,k,v -> qh,kh,vh (one 768-block dispatch)
  gemm256f<<<768, 512, 0, stream>>>(q, k, v, WT, qh);

  transpose_v<<<dim3(32, 8, BHN), tb, 0, stream>>>(vh, vhT);
  score_sm<<<256, 256, 0, stream>>>(qh, kh, mask, att);
  gemm_tn<2><<<dim3(8, 2, BHN), 256, 0, stream>>>(att, vhT, x, 256, 256, 256, 1024,
                                                  (long)65536, (long)262144, 0);
  gemm256<0><<<256, 512, 0, stream>>>(x, WT + (size_t)3145728, out);
}

// Round 9
// 271.691 us; speedup vs baseline: 1.1326x; 1.1326x over previous
//
#include <hip/hip_runtime.h>
#include <hip/hip_bf16.h>

typedef __bf16 bf16x8 __attribute__((ext_vector_type(8)));
typedef float f32x4 __attribute__((ext_vector_type(4)));
typedef unsigned short ushort_t;
typedef unsigned int uint_t;

#define HN 16
#define LSEQ 256
#define DD 1024
#define BB 4
#define SS 4096
#define MROWS (BB * SS) /* 16384 */
#define BHN (BB * HN)   /* 64 */

__device__ __forceinline__ ushort_t f2bf(float f) {
  uint_t u = __builtin_bit_cast(uint_t, f);
  u += 0x7fffu + ((u >> 16) & 1u); // RNE
  return (ushort_t)(u >> 16);
}
__device__ __forceinline__ uint_t pk2(float lo, float hi) {
  return (uint_t)f2bf(lo) | ((uint_t)f2bf(hi) << 16);
}

// ---------- fp32 -> bf16 bulk convert, up to 3 sources (z picks) ----------
__global__ __launch_bounds__(256) void cvt3(const float4* __restrict__ s0,
                                            const float4* __restrict__ s1,
                                            const float4* __restrict__ s2,
                                            uint4* __restrict__ out) {
  const int z = blockIdx.y;
  const float4* in = (z == 0) ? s0 : (z == 1) ? s1 : s2;
  const long i = (long)blockIdx.x * 256 + threadIdx.x;
  const float4 a = in[i * 2];
  const float4 b = in[i * 2 + 1];
  uint4 o;
  o.x = pk2(a.x, a.y);
  o.y = pk2(a.z, a.w);
  o.z = pk2(b.x, b.y);
  o.w = pk2(b.z, b.w);
  out[(long)z * 2097152 + i] = o;
}

// ---------- weight transpose x4: W fp32 [K][N] -> WT bf16 [N][K], packed ----------
__global__ __launch_bounds__(256) void transpose_w4(const float* __restrict__ W0,
                                                    const float* __restrict__ W1,
                                                    const float* __restrict__ W2,
                                                    const float* __restrict__ W3,
                                                    ushort_t* __restrict__ WT) {
  __shared__ float tile[32][33];
  const int z = blockIdx.z;
  const float* W = (z == 0) ? W0 : (z == 1) ? W1 : (z == 2) ? W2 : W3;
  ushort_t* dst = WT + (long)z * 1048576;
  const int tx = threadIdx.x, ty = threadIdx.y;
  const int bn = blockIdx.x * 32, bk = blockIdx.y * 32;
#pragma unroll
  for (int j = 0; j < 32; j += 8)
    tile[ty + j][tx] = W[(long)(bk + ty + j) * DD + bn + tx];
  __syncthreads();
#pragma unroll
  for (int j = 0; j < 32; j += 8)
    dst[(long)(bn + ty + j) * DD + bk + tx] = f2bf(tile[tx][ty + j]);
}

// ---------- vh transpose per (b,h): [256][1024] -> [1024][256] bf16 ----------
__global__ __launch_bounds__(256) void transpose_v(const ushort_t* __restrict__ vh,
                                                   ushort_t* __restrict__ vhT) {
  __shared__ ushort_t tile[32][33];
  const int tx = threadIdx.x, ty = threadIdx.y;
  const long zo = (long)blockIdx.z * (LSEQ * DD);
  const ushort_t* src = vh + zo;
  ushort_t* dst = vhT + zo;
  const int bd = blockIdx.x * 32; // d
  const int bl = blockIdx.y * 32; // l
#pragma unroll
  for (int j = 0; j < 32; j += 8)
    tile[ty + j][tx] = src[(long)(bl + ty + j) * DD + bd + tx];
  __syncthreads();
#pragma unroll
  for (int j = 0; j < 32; j += 8)
    dst[(long)(bd + ty + j) * LSEQ + bl + tx] = tile[tx][ty + j];
}

// ---------- fused scores + mask + softmax ----------
// per block: one (b,h), 64 q-rows, all 256 k-cols, K=1024. att bf16 out.
__global__ __launch_bounds__(256, 2) void score_sm(const ushort_t* __restrict__ qh,
                                                   const ushort_t* __restrict__ kh,
                                                   const int* __restrict__ mask,
                                                   ushort_t* __restrict__ att) {
  __shared__ char smemraw[81920]; // staging A 16KB + B 64KB; epilogue S 64KB aliases
  ushort_t* sA = (ushort_t*)smemraw;           // 2 x 4096 elems
  ushort_t* sB = (ushort_t*)(smemraw + 16384); // 2 x 16384 elems
  float* Sf = (float*)smemraw;                 // [64][256] fp32

  const int orig = blockIdx.x;
  const int wgid = (orig & 7) * 32 + (orig >> 3); // XCD-chunked, 256 % 8 == 0
  const int bh = wgid >> 2, rb = wgid & 3;
  const int b = bh >> 4;
  const ushort_t* A = qh + ((long)bh * 256 + rb * 64) * 1024;
  const ushort_t* Bk = kh + (long)bh * 256 * 1024;

  const int t = threadIdx.x, lane = t & 63, wid = t >> 6;
  const int fr = lane & 15, q = lane >> 4;
  const int wc = wid * 64;
  const int sw0 = (q ^ (fr & 7)) * 8;
  const int sw1 = ((4 + q) ^ (fr & 7)) * 8;

  int srcAo[2], dstA[2], srcBo[8], dstB[8];
#pragma unroll
  for (int i = 0; i < 2; ++i) {
    const int c = i * 256 + t, row = c >> 3, gc = (c & 7) ^ (row & 7);
    srcAo[i] = row * 1024 + gc * 8;
    dstA[i] = (i * 256 + (t & 192)) * 8;
  }
#pragma unroll
  for (int i = 0; i < 8; ++i) {
    const int c = i * 256 + t, row = c >> 3, gc = (c & 7) ^ (row & 7);
    srcBo[i] = row * 1024 + gc * 8;
    dstB[i] = (i * 256 + (t & 192)) * 8;
  }

  auto stage = [&](int buf, int kt) {
    const int ko = kt * 64;
#pragma unroll
    for (int i = 0; i < 2; ++i)
      __builtin_amdgcn_global_load_lds(
          (const __attribute__((address_space(1))) void*)(A + srcAo[i] + ko),
          (__attribute__((address_space(3))) void*)(sA + buf * 4096 + dstA[i]), 16, 0, 0);
#pragma unroll
    for (int i = 0; i < 8; ++i)
      __builtin_amdgcn_global_load_lds(
          (const __attribute__((address_space(1))) void*)(Bk + srcBo[i] + ko),
          (__attribute__((address_space(3))) void*)(sB + buf * 16384 + dstB[i]), 16, 0, 0);
  };

  f32x4 acc[4][4];
#pragma unroll
  for (int m = 0; m < 4; ++m)
#pragma unroll
    for (int n = 0; n < 4; ++n) acc[m][n] = (f32x4){0.f, 0.f, 0.f, 0.f};

  stage(0, 0);
  __syncthreads();
  int cur = 0;
  for (int kt = 0; kt < 16; ++kt) {
    if (kt < 15) stage(cur ^ 1, kt + 1);
    bf16x8 af[4][2], bfv[4][2];
    const ushort_t* bA = sA + cur * 4096;
    const ushort_t* bB = sB + cur * 16384;
#pragma unroll
    for (int m = 0; m < 4; ++m) {
      af[m][0] = *(const bf16x8*)(bA + (m * 16 + fr) * 64 + sw0);
      af[m][1] = *(const bf16x8*)(bA + (m * 16 + fr) * 64 + sw1);
    }
#pragma unroll
    for (int n = 0; n < 4; ++n) {
      bfv[n][0] = *(const bf16x8*)(bB + (wc + n * 16 + fr) * 64 + sw0);
      bfv[n][1] = *(const bf16x8*)(bB + (wc + n * 16 + fr) * 64 + sw1);
    }
#pragma unroll
    for (int m = 0; m < 4; ++m)
#pragma unroll
      for (int n = 0; n < 4; ++n) {
        acc[m][n] = __builtin_amdgcn_mfma_f32_16x16x32_bf16(af[m][0], bfv[n][0], acc[m][n], 0, 0, 0);
        acc[m][n] = __builtin_amdgcn_mfma_f32_16x16x32_bf16(af[m][1], bfv[n][1], acc[m][n], 0, 0, 0);
      }
    __syncthreads();
    cur ^= 1;
  }

#pragma unroll
  for (int m = 0; m < 4; ++m)
#pragma unroll
    for (int n = 0; n < 4; ++n)
#pragma unroll
      for (int r = 0; r < 4; ++r)
        Sf[(m * 16 + q * 4 + r) * 256 + wc + n * 16 + fr] = acc[m][n][r];
  __syncthreads();

#pragma unroll 2
  for (int i = 0; i < 16; ++i) {
    const int row = wid * 16 + i;
    const int gl = rb * 64 + row;
    const f32x4 sv = *(const f32x4*)&Sf[row * 256 + lane * 4];
    const int4 mv = *(const int4*)&mask[((long)b * 256 + gl) * 256 + lane * 4];
    float s[4];
    s[0] = (mv.x == 0) ? 1e-9f : sv[0] * 0.03125f;
    s[1] = (mv.y == 0) ? 1e-9f : sv[1] * 0.03125f;
    s[2] = (mv.z == 0) ? 1e-9f : sv[2] * 0.03125f;
    s[3] = (mv.w == 0) ? 1e-9f : sv[3] * 0.03125f;
    float mx = fmaxf(fmaxf(s[0], s[1]), fmaxf(s[2], s[3]));
#pragma unroll
    for (int off = 32; off; off >>= 1) mx = fmaxf(mx, __shfl_xor(mx, off));
    float e[4], sum = 0.f;
#pragma unroll
    for (int j = 0; j < 4; ++j) {
      e[j] = __expf(s[j] - mx);
      sum += e[j];
    }
#pragma unroll
    for (int off = 32; off; off >>= 1) sum += __shfl_xor(sum, off);
    const float inv = 1.0f / sum;
    ushort4 o;
    o.x = f2bf(e[0] * inv);
    o.y = f2bf(e[1] * inv);
    o.z = f2bf(e[2] * inv);
    o.w = f2bf(e[3] * inv);
    *(ushort4*)&att[((long)bh * 256 + gl) * 256 + lane * 4] = o;
  }
}

// ---------- 128^2 TN GEMM (batched PV), bf16 pv-permute store ----------
__global__ __launch_bounds__(256, 2) void gemm_tn(const ushort_t* __restrict__ Ab,
                                                  const ushort_t* __restrict__ Btp,
                                                  void* __restrict__ Cp, int K, int ldA,
                                                  int ldB, int ldC, long batchA,
                                                  long batchB, long batchC) {
  __shared__ ushort_t smem[16384];
  ushort_t* sA = smem;
  ushort_t* sB = smem + 8192;

  const int bx = blockIdx.x, by = blockIdx.y, z = blockIdx.z;
  const int rowBase = by * 128;
  const int colBase = bx * 128;

  const int t = threadIdx.x;
  const int lane = t & 63;
  const int wid = t >> 6;
  const int wr = (wid >> 1) * 64;
  const int wc = (wid & 1) * 64;
  const int fr = lane & 15;
  const int fk = (lane >> 4) * 8;

  const ushort_t* Atile = Ab + batchA * z + (long)rowBase * ldA;
  const ushort_t* Btile = Btp + batchB * z + (long)colBase * ldB;

  f32x4 acc[4][4];
#pragma unroll
  for (int m = 0; m < 4; ++m)
#pragma unroll
    for (int n = 0; n < 4; ++n) acc[m][n] = (f32x4){0.f, 0.f, 0.f, 0.f};

  const int NT = K >> 5;

  auto stageAB = [&](int buf, int kt) {
    const long ko = (long)kt * 32;
#pragma unroll
    for (int i = 0; i < 2; ++i) {
      const int c = i * 256 + t;
      const int cw = i * 256 + (t & 192);
      __builtin_amdgcn_global_load_lds(
          (const __attribute__((address_space(1))) void*)(Atile + (long)(c >> 2) * ldA + ko +
                                                          (c & 3) * 8),
          (__attribute__((address_space(3))) void*)(sA + buf * 4096 + cw * 8), 16, 0, 0);
      __builtin_amdgcn_global_load_lds(
          (const __attribute__((address_space(1))) void*)(Btile + (long)(c >> 2) * ldB + ko +
                                                          (c & 3) * 8),
          (__attribute__((address_space(3))) void*)(sB + buf * 4096 + cw * 8), 16, 0, 0);
    }
  };

  stageAB(0, 0);
  __syncthreads();

  int cur = 0;
  for (int kt = 0; kt < NT; ++kt) {
    if (kt + 1 < NT) stageAB(cur ^ 1, kt + 1);

    bf16x8 af[4], bfv[4];
    const ushort_t* baseA = sA + cur * 4096 + fk;
    const ushort_t* baseB = sB + cur * 4096 + fk;
#pragma unroll
    for (int m = 0; m < 4; ++m) af[m] = *(const bf16x8*)(baseA + (wr + m * 16 + fr) * 32);
#pragma unroll
    for (int n = 0; n < 4; ++n) bfv[n] = *(const bf16x8*)(baseB + (wc + n * 16 + fr) * 32);

#pragma unroll
    for (int m = 0; m < 4; ++m)
#pragma unroll
      for (int n = 0; n < 4; ++n)
        acc[m][n] = __builtin_amdgcn_mfma_f32_16x16x32_bf16(af[m], bfv[n], acc[m][n], 0, 0, 0);

    __syncthreads();
    cur ^= 1;
  }

  const int rq = (lane >> 4) * 4;
#pragma unroll
  for (int m = 0; m < 4; ++m)
#pragma unroll
    for (int n = 0; n < 4; ++n)
#pragma unroll
      for (int r = 0; r < 4; ++r)
        smem[(wr + m * 16 + rq + r) * 128 + wc + n * 16 + fr] = f2bf(acc[m][n][r]);
  __syncthreads();
  ushort_t* Cb = (ushort_t*)Cp;
  const int c8 = (lane & 15) * 8;
#pragma unroll
  for (int i = 0; i < 8; ++i) {
    const int row = i * 16 + wid * 4 + (lane >> 4);
    const uint4 val = *(const uint4*)(smem + row * 128 + c8);
    const int l = rowBase + row;
    const int orow = ((z >> 4) << 12) + l * 16 + (z & 15); // b*4096 + l*16 + h
    *(uint4*)(Cb + (long)orow * 1024 + colBase + c8) = val;
  }
}

// ---------- 256^2 8-phase TN GEMM, z-batched, early-staged counted-vmcnt ----------
// C_z[M][1024] = A_z[M][1024] * Bt_z[1024][1024]^T ; K = 1024 fixed.
// Halves are partitioned across WAVES (wm / wn>>1), so ALL 4 stage-pieces of a
// tile must land before Ph1/Ph5-open. Schedule: B(T+2)@Ph3, A(T+2)@Ph4 (dbuf0
// free after Ph2/Ph3); B(T+3)@Ph7, A(T+3)@Ph8. Gates VM(8)@Ph4/Ph8-close drain
// the tile needed next phase; youngest drained stage has 4 phases (~1000cy) cover.
// Invariant entering each iteration: outstanding = next tile's 8 loads.
#define SBAR() asm volatile("s_barrier" ::: "memory")
#define LGKM0() asm volatile("s_waitcnt lgkmcnt(0)" ::: "memory")
#define VM(N) asm volatile("s_waitcnt vmcnt(" #N ")" ::: "memory")

template <int SMODE>
__global__ __launch_bounds__(512, 1) void gemm256(const ushort_t* __restrict__ A0,
                                                  const ushort_t* __restrict__ A1,
                                                  const ushort_t* __restrict__ A2,
                                                  const ushort_t* __restrict__ Btp,
                                                  void* __restrict__ Cp, long bStrideZ,
                                                  long cStrideZ) {
  __shared__ ushort_t sm[65536]; // 128 KiB

  const int orig = blockIdx.x;
  const int cpx = (int)gridDim.x >> 3;
  const int wgid = (orig & 7) * cpx + (orig >> 3); // bijective (grid % 8 == 0)
  const int z = wgid >> 8;
  const int tile = wgid & 255;
  const int by = tile >> 2, bx = tile & 3;
  const int rowBase = by * 256, colBase = bx * 256;

  const ushort_t* Ab = (z == 0) ? A0 : (z == 1) ? A1 : A2;
  const ushort_t* Bt = Btp + bStrideZ * z;

  const int t = threadIdx.x;
  const int lane = t & 63;
  const int wid = t >> 6;
  const int wm = wid >> 2; // 0..1
  const int wn = wid & 3;  // 0..3
  const int fr = lane & 15;
  const int q = lane >> 4;

  const int sw0 = ((q ^ (fr & 7)) * 8);
  const int sw1 = (((4 + q) ^ (fr & 7)) * 8);
  const int aoff0 = fr * 64 + sw0;
  const int aoff1 = fr * 64 + sw1;
  const int bbase = ((wn & 1) * 64 + fr) * 64;
  const int boff0 = bbase + sw0;
  const int boff1 = bbase + sw1;

  const ushort_t* srcA[2][2];
  const ushort_t* srcB[2][2];
  int ldsoff[2];
#pragma unroll
  for (int i = 0; i < 2; ++i) {
    const int c = i * 512 + t;
    const int rowc = c >> 3;
    const int gc = (c & 7) ^ (rowc & 7);
    srcA[0][i] = Ab + (long)(rowBase + rowc) * 1024 + gc * 8;
    srcA[1][i] = Ab + (long)(rowBase + 128 + rowc) * 1024 + gc * 8;
    srcB[0][i] = Bt + (long)(colBase + rowc) * 1024 + gc * 8;
    srcB[1][i] = Bt + (long)(colBase + 128 + rowc) * 1024 + gc * 8;
    ldsoff[i] = (c & ~63) * 8;
  }

#define STAGE(kind, h, T)                                                                   \
  do {                                                                                      \
    ushort_t* _d = sm + ((kind) ? 32768 : 0) + ((T) & 1) * 16384 + (h) * 8192;              \
    const ushort_t* _s0 = ((kind) ? srcB[h][0] : srcA[h][0]) + (long)(T) * 64;              \
    __builtin_amdgcn_global_load_lds((const __attribute__((address_space(1))) void*)_s0,    \
                                     (__attribute__((address_space(3))) void*)(_d + ldsoff[0]), \
                                     16, 0, 0);                                             \
    const ushort_t* _s1 = ((kind) ? srcB[h][1] : srcA[h][1]) + (long)(T) * 64;              \
    __builtin_amdgcn_global_load_lds((const __attribute__((address_space(1))) void*)_s1,    \
                                     (__attribute__((address_space(3))) void*)(_d + ldsoff[1]), \
                                     16, 0, 0);                                             \
  } while (0)

  f32x4 acc[8][4];
#pragma unroll
  for (int m = 0; m < 8; ++m)
#pragma unroll
    for (int n = 0; n < 4; ++n) acc[m][n] = (f32x4){0.f, 0.f, 0.f, 0.f};

  bf16x8 af[4][2], bf0[2][2], bf1[2][2];

#define LDA4(dbuf, msub)                                                         \
  do {                                                                           \
    const ushort_t* _b = sm + (dbuf)*16384 + wm * 8192 + (msub)*4096;            \
    _Pragma("unroll") for (int m2 = 0; m2 < 4; ++m2) {                           \
      af[m2][0] = *(const bf16x8*)(_b + m2 * 1024 + aoff0);                      \
      af[m2][1] = *(const bf16x8*)(_b + m2 * 1024 + aoff1);                      \
    }                                                                            \
  } while (0)

#define LDB2(dbuf, nsub, bfv)                                                    \
  do {                                                                           \
    const ushort_t* _b = sm + 32768 + (dbuf)*16384 + (wn >> 1) * 8192 + (nsub)*2048; \
    _Pragma("unroll") for (int n2 = 0; n2 < 2; ++n2) {                           \
      bfv[n2][0] = *(const bf16x8*)(_b + n2 * 1024 + boff0);                     \
      bfv[n2][1] = *(const bf16x8*)(_b + n2 * 1024 + boff1);                     \
    }                                                                            \
  } while (0)

#define MMQ(msub, nsub, bfv)                                                     \
  do {                                                                           \
    _Pragma("unroll") for (int m2 = 0; m2 < 4; ++m2)                             \
        _Pragma("unroll") for (int n2 = 0; n2 < 2; ++n2) {                       \
      acc[(msub)*4 + m2][(nsub)*2 + n2] = __builtin_amdgcn_mfma_f32_16x16x32_bf16( \
          af[m2][0], bfv[n2][0], acc[(msub)*4 + m2][(nsub)*2 + n2], 0, 0, 0);    \
      acc[(msub)*4 + m2][(nsub)*2 + n2] = __builtin_amdgcn_mfma_f32_16x16x32_bf16( \
          af[m2][1], bfv[n2][1], acc[(msub)*4 + m2][(nsub)*2 + n2], 0, 0, 0);    \
    }                                                                            \
  } while (0)

#define PH_OPEN() SBAR(); LGKM0(); __builtin_amdgcn_s_setprio(1)
#define PH_CLOSE() __builtin_amdgcn_s_setprio(0); SBAR()

  const int NT = 16; // K=1024, K-tiles of 64
  const int NI = 8;

  // prologue: tiles 0 and 1 fully staged; VM(8) drains ALL of tile0 (leaves tile1's 8)
  STAGE(0, 0, 0);
  STAGE(0, 1, 0);
  STAGE(1, 0, 0);
  STAGE(1, 1, 0);
  STAGE(0, 0, 1);
  STAGE(0, 1, 1);
  STAGE(1, 0, 1);
  STAGE(1, 1, 1);
  VM(8);
  SBAR();

  for (int it = 0; it < NI - 1; ++it) {
    const int T0 = 2 * it;
    // Ph1 (reads dbuf0: A+B, all halves across waves)
    LDA4(0, 0);
    LDB2(0, 0, bf0);
    PH_OPEN(); MMQ(0, 0, bf0); PH_CLOSE();
    // Ph2 (last dbuf0-B read)
    LDB2(0, 1, bf1);
    PH_OPEN(); MMQ(0, 1, bf1); PH_CLOSE();
    // Ph3 (last dbuf0-A read) + stage B(T0+2) into dbuf0-B (free since Ph2-close)
    LDA4(0, 1);
    STAGE(1, 0, T0 + 2);
    STAGE(1, 1, T0 + 2);
    PH_OPEN(); MMQ(1, 1, bf1); PH_CLOSE();
    // Ph4: stage A(T0+2) into dbuf0-A (free since Ph3-close); gate tile T0+1
    STAGE(0, 0, T0 + 2);
    STAGE(0, 1, T0 + 2);
    SBAR();
    __builtin_amdgcn_s_setprio(1);
    MMQ(1, 0, bf0);
    __builtin_amdgcn_s_setprio(0);
    VM(8); // drains tile T0+1 (issued prev Ph7/Ph8, >=4 phases cover); leaves T0+2
    SBAR();
    // Ph5 (reads dbuf1)
    LDA4(1, 0);
    LDB2(1, 0, bf0);
    PH_OPEN(); MMQ(0, 0, bf0); PH_CLOSE();
    // Ph6 (last dbuf1-B read)
    LDB2(1, 1, bf1);
    PH_OPEN(); MMQ(0, 1, bf1); PH_CLOSE();
    // Ph7 (last dbuf1-A read) + stage B(T0+3) into dbuf1-B
    LDA4(1, 1);
    STAGE(1, 0, T0 + 3);
    STAGE(1, 1, T0 + 3);
    PH_OPEN(); MMQ(1, 1, bf1); PH_CLOSE();
    // Ph8: stage A(T0+3) into dbuf1-A; gate tile T0+2
    STAGE(0, 0, T0 + 3);
    STAGE(0, 1, T0 + 3);
    SBAR();
    __builtin_amdgcn_s_setprio(1);
    MMQ(1, 0, bf0);
    __builtin_amdgcn_s_setprio(0);
    VM(8); // drains tile T0+2 (issued Ph3/Ph4, >=4 phases cover); leaves T0+3
    SBAR();
  }

  { // peeled last iteration (tiles 14,15): no new stages
    LDA4(0, 0);
    LDB2(0, 0, bf0);
    PH_OPEN(); MMQ(0, 0, bf0); PH_CLOSE();
    LDB2(0, 1, bf1);
    PH_OPEN(); MMQ(0, 1, bf1); PH_CLOSE();
    LDA4(0, 1);
    PH_OPEN(); MMQ(1, 1, bf1); PH_CLOSE();
    SBAR();
    __builtin_amdgcn_s_setprio(1);
    MMQ(1, 0, bf0);
    __builtin_amdgcn_s_setprio(0);
    VM(0); // drains tile15 (issued prev Ph7/Ph8, >=4 phases cover)
    SBAR();
    LDA4(1, 0);
    LDB2(1, 0, bf0);
    PH_OPEN(); MMQ(0, 0, bf0); PH_CLOSE();
    LDB2(1, 1, bf1);
    PH_OPEN(); MMQ(0, 1, bf1); PH_CLOSE();
    LDA4(1, 1);
    PH_OPEN(); MMQ(1, 1, bf1); PH_CLOSE();
    SBAR();
    MMQ(1, 0, bf0);
    SBAR();
  }

  const int rq = q * 4;
  if constexpr (SMODE == 0) {
    float* Cf = (float*)Cp + cStrideZ * z;
#pragma unroll
    for (int m = 0; m < 8; ++m)
#pragma unroll
      for (int n = 0; n < 4; ++n)
#pragma unroll
        for (int r = 0; r < 4; ++r) {
          const int row = rowBase + wm * 128 + m * 16 + rq + r;
          const int col = colBase + wn * 64 + n * 16 + fr;
          Cf[(long)row * 1024 + col] = acc[m][n][r];
        }
  } else {
#pragma unroll
    for (int m = 0; m < 8; ++m)
#pragma unroll
      for (int n = 0; n < 4; ++n)
#pragma unroll
        for (int r = 0; r < 4; ++r) {
          const int row = wm * 128 + m * 16 + rq + r;
          const int col = wn * 64 + n * 16 + fr;
          sm[row * 256 + (((col >> 3) ^ (row & 7)) * 8) + (col & 7)] = f2bf(acc[m][n][r]);
        }
    __syncthreads();
    ushort_t* Cb = (ushort_t*)Cp + cStrideZ * z;
    const int cc = t & 31;
    const int r0 = t >> 5;
#pragma unroll
    for (int i = 0; i < 16; ++i) {
      const int row = r0 + i * 16;
      const uint4 val = *(const uint4*)(sm + row * 256 + ((cc ^ (row & 7)) * 8));
      const int grow = rowBase + row; // = b*4096 + s, s = l*16+h
      const int b = grow >> 12;
      const int s = grow & 4095;
      const int orow = ((b << 4) + (s & 15)) * 256 + (s >> 4); // (b*16+h)*256 + l
      *(uint4*)(Cb + (long)orow * 1024 + colBase + cc * 8) = val;
    }
  }
#undef STAGE
#undef LDA4
#undef LDB2
#undef MMQ
#undef PH_OPEN
#undef PH_CLOSE
}

extern "C" void kernel_launch(void* const* d_in, const int* in_sizes, int n_in,
                              void* d_out, int out_size, void* d_ws, size_t ws_size,
                              hipStream_t stream) {
  const float* q = (const float*)d_in[0];
  const float* k = (const float*)d_in[1];
  const float* v = (const float*)d_in[2];
  const int* mask = (const int*)d_in[3];
  const float* Wq = (const float*)d_in[4];
  const float* Wk = (const float*)d_in[5];
  const float* Wv = (const float*)d_in[6];
  const float* Wo = (const float*)d_in[7];
  float* out = (float*)d_out;

  char* ws = (char*)d_ws;
  const size_t MB = 1024 * 1024;
  ushort_t* WT = (ushort_t*)ws; // packed [4][1024][1024] bf16: Wq,Wk,Wv,Wo (8MB)
  const dim3 tb(32, 8);
  transpose_w4<<<dim3(32, 32, 4), tb, 0, stream>>>(Wq, Wk, Wv, Wo, WT);

  const bool big = ws_size >= (size_t)200 * MB;

  if (big) {
    // layout: WT 0..8 | qkvb 8..104 | qh 104..136 | kh 136..168 | vh 168..200
    // after proj (qkvb dead): vhT 8..40 | att 40..48 | x 48..80
    ushort_t* qkvb = (ushort_t*)(ws + 8 * MB);
    ushort_t* qh = (ushort_t*)(ws + 104 * MB);
    ushort_t* kh = (ushort_t*)(ws + 136 * MB);
    ushort_t* vh = (ushort_t*)(ws + 168 * MB);
    ushort_t* vhT = (ushort_t*)(ws + 8 * MB);
    ushort_t* att = (ushort_t*)(ws + 40 * MB);
    ushort_t* x = (ushort_t*)(ws + 48 * MB);

    cvt3<<<dim3(8192, 3), 256, 0, stream>>>((const float4*)q, (const float4*)k,
                                            (const float4*)v, (uint4*)qkvb);
    gemm256<1><<<768, 512, 0, stream>>>(qkvb, qkvb + (size_t)16777216,
                                        qkvb + (size_t)33554432, WT, qh, 1 << 20,
                                        (long)16777216);
    transpose_v<<<dim3(32, 8, BHN), tb, 0, stream>>>(vh, vhT);
    score_sm<<<256, 256, 0, stream>>>(qh, kh, mask, att);
    gemm_tn<<<dim3(8, 2, BHN), 256, 0, stream>>>(att, vhT, x, 256, 256, 256, 1024,
                                                 (long)65536, (long)262144, 0);
    gemm256<0><<<256, 512, 0, stream>>>(x, x, x, WT + (size_t)3145728, out, 0, 0);
  } else {
    // serial fallback (peak 168MB)
    ushort_t* qb = (ushort_t*)(ws + 8 * MB);
    ushort_t* qh = (ushort_t*)(ws + 40 * MB);
    ushort_t* kh = (ushort_t*)(ws + 72 * MB);
    ushort_t* vh = (ushort_t*)(ws + 104 * MB);
    ushort_t* vhT = (ushort_t*)(ws + 136 * MB);
    ushort_t* att = (ushort_t*)(ws + 8 * MB);
    ushort_t* x = (ushort_t*)(ws + 16 * MB);

    cvt3<<<dim3(8192, 1), 256, 0, stream>>>((const float4*)q, (const float4*)q,
                                            (const float4*)q, (uint4*)qb);
    gemm256<1><<<256, 512, 0, stream>>>(qb, qb, qb, WT, qh, 0, 0);
    cvt3<<<dim3(8192, 1), 256, 0, stream>>>((const float4*)k, (const float4*)k,
                                            (const float4*)k, (uint4*)qb);
    gemm256<1><<<256, 512, 0, stream>>>(qb, qb, qb, WT + (size_t)1048576, kh, 0, 0);
    cvt3<<<dim3(8192, 1), 256, 0, stream>>>((const float4*)v, (const float4*)v,
                                            (const float4*)v, (uint4*)qb);
    gemm256<1><<<256, 512, 0, stream>>>(qb, qb, qb, WT + (size_t)2097152, vh, 0, 0);
    transpose_v<<<dim3(32, 8, BHN), tb, 0, stream>>>(vh, vhT);
    score_sm<<<256, 256, 0, stream>>>(qh, kh, mask, att);
    gemm_tn<<<dim3(8, 2, BHN), 256, 0, stream>>>(att, vhT, x, 256, 256, 256, 1024,
                                                 (long)65536, (long)262144, 0);
    gemm256<0><<<256, 512, 0, stream>>>(x, x, x, WT + (size_t)3145728, out, 0, 0);
  }
}